// Round 16
// baseline (189.483 us; speedup 1.0000x reference)
//
#include <hip/hip_runtime.h>
#include <hip/hip_bf16.h>
#include <hip/hip_fp16.h>
#include <math.h>

// ---------------------------------------------------------------------------
// GraphConv GNN, round 15: occupancy-oriented GEMM retile (128x64 tile,
// BK=32, 24KB LDS -> 6 blocks/CU, 1564-block grid) + head retile (64 rows,
// double-buffered). CSR build / gathers / prep unchanged from R14.
// ---------------------------------------------------------------------------

typedef __attribute__((ext_vector_type(8))) short short8;
typedef __attribute__((ext_vector_type(4))) float f32x4;

static __device__ __forceinline__ float bf2f(unsigned short u) {
    return __uint_as_float(((unsigned)u) << 16);
}

// ---- fp8 e4m3 helpers -----------------------------------------------------
static __device__ __forceinline__ void fp8x4_to_f32(unsigned u, float* o) {
#if __has_builtin(__builtin_amdgcn_cvt_pk_f32_fp8)
    auto lo = __builtin_amdgcn_cvt_pk_f32_fp8((int)u, false);
    auto hi = __builtin_amdgcn_cvt_pk_f32_fp8((int)u, true);
    o[0] = lo[0]; o[1] = lo[1]; o[2] = hi[0]; o[3] = hi[1];
#else
#pragma unroll
    for (int i = 0; i < 4; ++i) {
        unsigned b = (u >> (8 * i)) & 0xffu;
        unsigned short hb = (unsigned short)(((b & 0x80u) << 8) | ((b & 0x7fu) << 7));
        o[i] = __half2float(__ushort_as_half(hb)) * 256.0f;
    }
#endif
}

static __device__ __forceinline__ unsigned f32_to_fp8(float f) {
    __half h = __float2half(f * 0.00390625f);            // 2^-8
    unsigned short hb = __half_as_ushort(h);
    unsigned mag = hb & 0x7fffu;
    unsigned s = (hb >> 8) & 0x80u;
    unsigned v = (mag + 0x3fu + ((mag >> 7) & 1u)) >> 7; // RNE
    if (v > 0x7eu) v = 0x7eu;                            // clamp below NaN
    return s | v;
}

#define BH_EPB 16

// ---- fused prep: bucket partial-histograms + x->bf16+fp8 + weight transposes
__global__ __launch_bounds__(256) void prep_all(
    const int* __restrict__ ei, int E, int hist_blocks,
    int* __restrict__ bh_part,
    const float* __restrict__ x, __hip_bfloat16* __restrict__ xb,
    unsigned char* __restrict__ xb8, int NX8,
    const float* __restrict__ w1_rel, const float* __restrict__ w1_root,
    const float* __restrict__ w2_rel, const float* __restrict__ w2_root,
    const float* __restrict__ w_lin,
    __hip_bfloat16* __restrict__ w1relT, __hip_bfloat16* __restrict__ w1rootT,
    __hip_bfloat16* __restrict__ w2relT, __hip_bfloat16* __restrict__ w2rootT,
    __hip_bfloat16* __restrict__ wlinT)
{
    __shared__ int lh[256];
    const int t = threadIdx.x;
    if (blockIdx.x < (unsigned)hist_blocks) {
        lh[t] = 0;
        __syncthreads();
        const int base = blockIdx.x * (256 * BH_EPB);
#pragma unroll
        for (int i = 0; i < BH_EPB; ++i) {
            int e = base + i * 256 + t;
            if (e < E) atomicAdd(&lh[ei[E + e] >> 8], 1);
        }
        __syncthreads();
        bh_part[blockIdx.x * 256 + t] = lh[t];   // coalesced row
        return;
    }
    int idx = (blockIdx.x - hist_blocks) * 256 + t;
    if (idx < NX8) {   // x -> bf16 + fp8, 8 elems/thread
        float4 a = *(const float4*)&x[(size_t)idx * 8];
        float4 b = *(const float4*)&x[(size_t)idx * 8 + 4];
        float f[8] = { a.x, a.y, a.z, a.w, b.x, b.y, b.z, b.w };
        __hip_bfloat16 o[8];
#pragma unroll
        for (int i = 0; i < 8; ++i) o[i] = __float2bfloat16(f[i]);
        *(short8*)&xb[(size_t)idx * 8] = *(short8*)o;
        unsigned p0 = 0, p1 = 0;
#pragma unroll
        for (int i = 0; i < 4; ++i) p0 |= f32_to_fp8(f[i]) << (8 * i);
#pragma unroll
        for (int i = 0; i < 4; ++i) p1 |= f32_to_fp8(f[4 + i]) << (8 * i);
        *(uint2*)&xb8[(size_t)idx * 8] = make_uint2(p0, p1);
        return;
    }
    idx -= NX8;
    if (idx < 65536) {                       // w1_rel/w1_root [128,256] -> [256,128]
        const float* src = (idx < 32768) ? w1_rel : w1_root;
        __hip_bfloat16* dst = (idx < 32768) ? w1relT : w1rootT;
        int i = idx & 32767;
        int k = i >> 8, c = i & 255;
        dst[c * 128 + k] = __float2bfloat16(src[i]);
    } else if (idx < 196608) {               // w2_rel/w2_root [256,256]^T
        int j = idx - 65536;
        const float* src = (j < 65536) ? w2_rel : w2_root;
        __hip_bfloat16* dst = (j < 65536) ? w2relT : w2rootT;
        int i = j & 65535;
        int k = i >> 8, c = i & 255;
        dst[c * 256 + k] = __float2bfloat16(src[i]);
    } else if (idx < 229376) {               // w_lin [512,40] -> [2][64][256]
        int i = idx - 196608;
        int seg = i >> 14, c = (i >> 8) & 63, k = i & 255;
        float v = (c < 40) ? w_lin[(size_t)(seg * 256 + k) * 40 + c] : 0.f;
        wlinT[i] = __float2bfloat16(v);
    }
}

// ---- reduce partial histograms (8-deep MLP) + scan ------------------------
__global__ __launch_bounds__(256) void scan_bsum(
    const int* __restrict__ bh_part, int hist_blocks,
    int* __restrict__ bpre, int* __restrict__ bend,
    int* __restrict__ bucket_cursor)
{
    __shared__ int sh[256];
    const int t = threadIdx.x;
    int a0 = 0, a1 = 0, a2 = 0, a3 = 0, a4 = 0, a5 = 0, a6 = 0, a7 = 0;
    int b = 0;
    for (; b + 8 <= hist_blocks; b += 8) {
        a0 += bh_part[(b + 0) * 256 + t];
        a1 += bh_part[(b + 1) * 256 + t];
        a2 += bh_part[(b + 2) * 256 + t];
        a3 += bh_part[(b + 3) * 256 + t];
        a4 += bh_part[(b + 4) * 256 + t];
        a5 += bh_part[(b + 5) * 256 + t];
        a6 += bh_part[(b + 6) * 256 + t];
        a7 += bh_part[(b + 7) * 256 + t];
    }
    for (; b < hist_blocks; ++b) a0 += bh_part[b * 256 + t];
    int v = ((a0 + a1) + (a2 + a3)) + ((a4 + a5) + (a6 + a7));
    sh[t] = v;
    __syncthreads();
#pragma unroll
    for (int off = 1; off < 256; off <<= 1) {
        int u = (t >= off) ? sh[t - off] : 0;
        __syncthreads();
        sh[t] += u;
        __syncthreads();
    }
    bpre[t]          = sh[t] - v;
    bend[t]          = sh[t];
    bucket_cursor[t] = sh[t] - v;
}

// ---- fill pass 1: partition edges into 256-node buckets -------------------
#define P1_EPB 8
__global__ __launch_bounds__(256) void part_kernel(
    const int* __restrict__ ei, const float* __restrict__ ew,
    int* __restrict__ bucket_cursor, uint2* __restrict__ part, int E)
{
    __shared__ int lhist[256];
    __shared__ int gbase[256];
    const int t = threadIdx.x;
    const int base = blockIdx.x * (256 * P1_EPB);
    lhist[t] = 0;
    __syncthreads();

    int pk[P1_EPB];
#pragma unroll
    for (int i = 0; i < P1_EPB; ++i) {
        int e = base + i * 256 + t;
        if (e < E) {
            int b = ei[E + e] >> 8;
            int r = atomicAdd(&lhist[b], 1);
            pk[i] = (b << 16) | r;
        } else pk[i] = -1;
    }
    __syncthreads();
    if (lhist[t] > 0) gbase[t] = atomicAdd(&bucket_cursor[t], lhist[t]);
    __syncthreads();
#pragma unroll
    for (int i = 0; i < P1_EPB; ++i) {
        if (pk[i] >= 0) {
            int e = base + i * 256 + t;
            int d = ei[E + e];
            unsigned short w16 = __half_as_ushort(__float2half(ew[e]));
            unsigned rec = ((unsigned)w16 << 16) | (unsigned)ei[e];
            int pos = gbase[pk[i] >> 16] + (pk[i] & 0xffff);
            part[pos] = make_uint2(rec, (unsigned)d);
        }
    }
}

// ---- fill pass 2: per-bucket CSR build + local scatter --------------------
__global__ __launch_bounds__(256) void fill2_kernel(
    const uint2* __restrict__ part, const int* __restrict__ bpre,
    const int* __restrict__ bend, int* __restrict__ row_ptr,
    unsigned* __restrict__ edges, int n)
{
    __shared__ int lcnt[256];
    __shared__ int excl[256];
    __shared__ int curs[256];
    const int b = blockIdx.x;
    const int t = threadIdx.x;
    const int node0 = b << 8;
    lcnt[t] = 0;
    __syncthreads();
    const int beg = bpre[b];
    const int end = bend[b];
    for (int i = beg + t; i < end; i += 256)
        atomicAdd(&lcnt[part[i].y & 255u], 1);
    __syncthreads();
    int v = lcnt[t];
    excl[t] = v;
    __syncthreads();
#pragma unroll
    for (int off = 1; off < 256; off <<= 1) {
        int u = (t >= off) ? excl[t - off] : 0;
        __syncthreads();
        excl[t] += u;
        __syncthreads();
    }
    const int base_t = beg + excl[t] - v;
    const int nd = node0 + t;
    if (nd <= n) row_ptr[nd] = base_t;
    curs[t] = base_t;
    __syncthreads();
    for (int i = beg + t; i < end; i += 256) {
        uint2 p = part[i];
        int slot = atomicAdd(&curs[p.y & 255u], 1);
        edges[slot] = p.x;
    }
}

// ---- gather (fp8 table, 4B edges): agg[v,:] = sum_e w_e * feat8[src_e,:] --
template <int C>
__global__ __launch_bounds__(256) void gather_fp8(
    const unsigned char* __restrict__ feat8,
    const unsigned* __restrict__ edges,
    const int*  __restrict__ rp,
    __hip_bfloat16* __restrict__ agg, int n)
{
    const int node = (blockIdx.x * 256 + threadIdx.x) >> 6;
    const int lane = threadIdx.x & 63;
    if (node >= n) return;
    const int beg = __builtin_amdgcn_readfirstlane(rp[node]);
    const int end = __builtin_amdgcn_readfirstlane(rp[node + 1]);

    constexpr int EPW = (C == 128) ? 8 : 4;
    constexpr int LPR = 64 / EPW;
    const int es = lane / LPR;
    const int ch = lane % LPR;
    const unsigned coff = (unsigned)ch * 16;

    float acc[16] = {};

    auto accum16 = [&](uint4 u, float w) {
        unsigned uu[4] = { u.x, u.y, u.z, u.w };
#pragma unroll
        for (int q = 0; q < 4; ++q) {
            float f[4];
            fp8x4_to_f32(uu[q], f);
#pragma unroll
            for (int i = 0; i < 4; ++i)
                acc[q * 4 + i] = fmaf(f[i], w, acc[q * 4 + i]);
        }
    };

    auto unpack_w = [](unsigned p) {
        return __half2float(__ushort_as_half((unsigned short)(p >> 16)));
    };

    for (int base = beg; base < end; base += 64) {
        const int m = min(64, end - base);
        unsigned ev = edges[base + ((lane < m) ? lane : (m - 1))];
        if (lane >= m) ev &= 0xffffu;

        int s = 0;
        for (; s + 2 * EPW <= m; s += 2 * EPW) {
            int j0 = s + es, j1 = j0 + EPW;
            unsigned p0 = (unsigned)__shfl((int)ev, j0, 64);
            unsigned p1 = (unsigned)__shfl((int)ev, j1, 64);
            uint4 u0 = *(const uint4*)(feat8 + (size_t)(p0 & 0xffffu) * C + coff);
            uint4 u1 = *(const uint4*)(feat8 + (size_t)(p1 & 0xffffu) * C + coff);
            accum16(u0, unpack_w(p0));
            accum16(u1, unpack_w(p1));
        }
        for (; s < m; s += EPW) {
            int j = min(s + es, 63);
            unsigned p = (unsigned)__shfl((int)ev, j, 64);
            uint4 u = *(const uint4*)(feat8 + (size_t)(p & 0xffffu) * C + coff);
            accum16(u, unpack_w(p));
        }
    }

#pragma unroll
    for (int k = 0; k < 16; ++k) {
        if constexpr (C == 128) {
            acc[k] += __shfl_xor(acc[k], 8, 64);
            acc[k] += __shfl_xor(acc[k], 16, 64);
            acc[k] += __shfl_xor(acc[k], 32, 64);
        } else {
            acc[k] += __shfl_xor(acc[k], 16, 64);
            acc[k] += __shfl_xor(acc[k], 32, 64);
        }
    }
    if (es == 0) {
        __hip_bfloat16 o[16];
#pragma unroll
        for (int k = 0; k < 16; ++k) o[k] = __float2bfloat16(acc[k]);
        __hip_bfloat16* op = agg + (size_t)node * C + ch * 16;
        *(short8*)op       = *(short8*)o;
        *(short8*)(op + 8) = *(short8*)(o + 8);
    }
}

// ---- MFMA GEMM: C = relu(A0@W0 + A1@W1 + bias), NC=256, bf16 in/out -------
// 128x64 tile, BK=32, 24KB LDS (6 blocks/CU), 2-phase pipeline,
// LDS-staged coalesced epilogue. grid = (M/128) * 4.
template <bool WRITE_FP8>
__global__ __launch_bounds__(256) void gemm_mfma(
    const __hip_bfloat16* __restrict__ A0, const __hip_bfloat16* __restrict__ A1,
    const __hip_bfloat16* __restrict__ W0T, const __hip_bfloat16* __restrict__ W1T,
    const float* __restrict__ bias,
    __hip_bfloat16* __restrict__ Cmat,
    unsigned char* __restrict__ Cfp8,
    int n, int K0, int K1)
{
    // layout: A buf0 [0,4096), A buf1 [4096,8192), B buf0 [8192,10240),
    //         B buf1 [10240,12288). Epilogue reuses [0,8192) as 128x64 tile.
    __shared__ __hip_bfloat16 smem[12288];   // 24 KB
    const int bm = blockIdx.x >> 2;
    const int bn = blockIdx.x & 3;
    const int row0 = bm * 128, col0 = bn * 64;
    const int t = threadIdx.x, lane = t & 63, wid = t >> 6;

    const int S0 = K0 >> 5;                  // BK = 32
    const int S  = S0 + (K1 >> 5);

    auto stage = [&](int buf, int s) {
        const __hip_bfloat16* A;
        const __hip_bfloat16* WT;
        int K, k0;
        if (s < S0) { A = A0; WT = W0T; K = K0; k0 = s << 5; }
        else        { A = A1; WT = W1T; K = K1; k0 = (s - S0) << 5; }
        __hip_bfloat16* Ab = smem + buf * 4096;
        __hip_bfloat16* Bb = smem + 8192 + buf * 2048;
        // A: 128 rows x 4 chunks (16B) = 512 chunks, 2 iters
#pragma unroll
        for (int i = 0; i < 2; ++i) {
            int idx = i * 256 + t;
            int r = idx >> 2, c = idx & 3;
            int gr = row0 + r; if (gr >= n) gr = n - 1;
            const __hip_bfloat16* srcA =
                A + (size_t)gr * K + k0 + ((c ^ (r & 3)) << 3);
            __builtin_amdgcn_global_load_lds(
                (const __attribute__((address_space(1))) void*)srcA,
                (__attribute__((address_space(3))) void*)&Ab[idx * 8], 16, 0, 0);
        }
        // B: 64 rows x 4 chunks = 256 chunks, 1 iter
        {
            int r = t >> 2, c = t & 3;
            const __hip_bfloat16* srcB =
                WT + (size_t)(col0 + r) * K + k0 + ((c ^ (r & 3)) << 3);
            __builtin_amdgcn_global_load_lds(
                (const __attribute__((address_space(1))) void*)srcB,
                (__attribute__((address_space(3))) void*)&Bb[t * 8], 16, 0, 0);
        }
    };

    f32x4 acc[2][4] = {};

    stage(0, 0);
    __syncthreads();

    for (int s = 0; s < S; ++s) {
        const int buf = s & 1;
        if (s + 1 < S) stage(buf ^ 1, s + 1);
        const __hip_bfloat16* Ab = smem + buf * 4096;
        const __hip_bfloat16* Bb = smem + 8192 + buf * 2048;
        const int cchunk = lane >> 4;        // 0..3
        short8 af[2], bfr[4];
#pragma unroll
        for (int m = 0; m < 2; ++m) {
            int r = wid * 32 + m * 16 + (lane & 15);
            af[m] = *(const short8*)&Ab[r * 32 + ((cchunk ^ (r & 3)) << 3)];
        }
#pragma unroll
        for (int nn = 0; nn < 4; ++nn) {
            int r = nn * 16 + (lane & 15);
            bfr[nn] = *(const short8*)&Bb[r * 32 + ((cchunk ^ (r & 3)) << 3)];
        }
#pragma unroll
        for (int m = 0; m < 2; ++m)
#pragma unroll
            for (int nn = 0; nn < 4; ++nn)
                acc[m][nn] = __builtin_amdgcn_mfma_f32_16x16x32_bf16(
                    af[m], bfr[nn], acc[m][nn], 0, 0, 0);
        __syncthreads();
    }

    // epilogue: bias+relu -> LDS 128x64 tile -> coalesced global writes
    __hip_bfloat16* Csh = smem;              // 8192 elems = 16 KB
#pragma unroll
    for (int nn = 0; nn < 4; ++nn) {
        int lcol = nn * 16 + (lane & 15);
        float b = bias[col0 + lcol];
#pragma unroll
        for (int m = 0; m < 2; ++m) {
#pragma unroll
            for (int rg = 0; rg < 4; ++rg) {
                int lrow = wid * 32 + m * 16 + ((lane >> 4) * 4) + rg;
                float v = fmaxf(acc[m][nn][rg] + b, 0.f);
                Csh[lrow * 64 + lcol] = __float2bfloat16(v);
            }
        }
    }
    __syncthreads();

    // bf16 out: 128 rows x 8 chunks(16B) = 1024 chunks, 4 iters
#pragma unroll
    for (int it = 0; it < 4; ++it) {
        int idx = it * 256 + t;
        int r = idx >> 3, c8 = idx & 7;
        if (row0 + r < n)
            *(short8*)(Cmat + (size_t)(row0 + r) * 256 + col0 + c8 * 8) =
                *(const short8*)&Csh[r * 64 + c8 * 8];
    }
    if constexpr (WRITE_FP8) {
        // fp8 out: 128 rows x 4 chunks(16B) = 512 chunks, 2 iters
#pragma unroll
        for (int it = 0; it < 2; ++it) {
            int idx = it * 256 + t;
            int r = idx >> 2, c16 = idx & 3;
            if (row0 + r < n) {
                const __hip_bfloat16* src = &Csh[r * 64 + c16 * 16];
                unsigned w[4];
#pragma unroll
                for (int q = 0; q < 4; ++q) {
                    unsigned p = 0;
#pragma unroll
                    for (int i = 0; i < 4; ++i)
                        p |= f32_to_fp8(__bfloat162float(src[q * 4 + i])) << (8 * i);
                    w[q] = p;
                }
                *(uint4*)(Cfp8 + (size_t)(row0 + r) * 256 + col0 + c16 * 16) =
                    make_uint4(w[0], w[1], w[2], w[3]);
            }
        }
    }
}

// ---- head: out = log_softmax([x1|x2] @ w_lin + b_lin), MFMA fused ---------
// 64 rows/block, double-buffered (32KB LDS), grid = ceil(N/64).
__global__ __launch_bounds__(256) void head_mfma(
    const __hip_bfloat16* __restrict__ X1, const __hip_bfloat16* __restrict__ X2,
    const __hip_bfloat16* __restrict__ WLT,   // [2][64][256]
    const float* __restrict__ b_lin,
    float* __restrict__ out, int n)
{
    // A buf0 [0,4096), A buf1 [4096,8192), B buf0 [8192,12288), B buf1 [12288,16384)
    __shared__ __hip_bfloat16 smem[16384];   // 32 KB
    const int row0 = blockIdx.x * 64;
    const int t = threadIdx.x, lane = t & 63, wid = t >> 6;

    auto stage = [&](int buf, int s) {
        const int seg = s >> 2;
        const int k0  = (s & 3) << 6;
        const __hip_bfloat16* A  = seg ? X2 : X1;
        const __hip_bfloat16* WT = WLT + seg * 64 * 256;
        __hip_bfloat16* Ab = smem + buf * 4096;
        __hip_bfloat16* Bb = smem + 8192 + buf * 4096;
        // A: 64 rows x 8 chunks = 512 chunks, 2 iters
#pragma unroll
        for (int i = 0; i < 2; ++i) {
            int idx = i * 256 + t;
            int r = idx >> 3, c = idx & 7;
            int gr = row0 + r; if (gr >= n) gr = n - 1;
            const __hip_bfloat16* srcA =
                A + (size_t)gr * 256 + k0 + ((c ^ (r & 7)) << 3);
            __builtin_amdgcn_global_load_lds(
                (const __attribute__((address_space(1))) void*)srcA,
                (__attribute__((address_space(3))) void*)&Ab[idx * 8], 16, 0, 0);
        }
        // B: 64 rows x 8 chunks = 512 chunks, 2 iters
#pragma unroll
        for (int i = 0; i < 2; ++i) {
            int idx = i * 256 + t;
            int r = idx >> 3, c = idx & 7;
            const __hip_bfloat16* srcB =
                WT + (size_t)r * 256 + k0 + ((c ^ (r & 7)) << 3);
            __builtin_amdgcn_global_load_lds(
                (const __attribute__((address_space(1))) void*)srcB,
                (__attribute__((address_space(3))) void*)&Bb[idx * 8], 16, 0, 0);
        }
    };

    f32x4 acc[4] = {};

    stage(0, 0);
    __syncthreads();

    for (int s = 0; s < 8; ++s) {
        const int buf = s & 1;
        if (s + 1 < 8) stage(buf ^ 1, s + 1);
        const __hip_bfloat16* Ab = smem + buf * 4096;
        const __hip_bfloat16* Bb = smem + 8192 + buf * 4096;
#pragma unroll
        for (int kh = 0; kh < 2; ++kh) {
            const int cchunk = kh * 4 + (lane >> 4);
            int ra = wid * 16 + (lane & 15);
            short8 af = *(const short8*)&Ab[ra * 64 + ((cchunk ^ (ra & 7)) << 3)];
            short8 bfr[4];
#pragma unroll
            for (int nn = 0; nn < 4; ++nn) {
                int r = nn * 16 + (lane & 15);
                bfr[nn] = *(const short8*)&Bb[r * 64 + ((cchunk ^ (r & 7)) << 3)];
            }
#pragma unroll
            for (int nn = 0; nn < 4; ++nn)
                acc[nn] = __builtin_amdgcn_mfma_f32_16x16x32_bf16(
                    af, bfr[nn], acc[nn], 0, 0, 0);
        }
        __syncthreads();
    }

    const int cl = lane & 15;
    float bb[4];
#pragma unroll
    for (int nn = 0; nn < 4; ++nn) {
        int col = nn * 16 + cl;
        bb[nn] = (col < 40) ? b_lin[col] : 0.f;
    }
#pragma unroll
    for (int rg = 0; rg < 4; ++rg) {
        float v[4];
        float mx = -1e30f;
#pragma unroll
        for (int nn = 0; nn < 4; ++nn) {
            int col = nn * 16 + cl;
            v[nn] = acc[nn][rg] + bb[nn];
            if (col < 40) mx = fmaxf(mx, v[nn]);
        }
#pragma unroll
        for (int off = 1; off < 16; off <<= 1)
            mx = fmaxf(mx, __shfl_xor(mx, off, 64));
        float s = 0.f;
#pragma unroll
        for (int nn = 0; nn < 4; ++nn) {
            int col = nn * 16 + cl;
            if (col < 40) s += expf(v[nn] - mx);
        }
#pragma unroll
        for (int off = 1; off < 16; off <<= 1)
            s += __shfl_xor(s, off, 64);
        float ls = logf(s);
        int row = row0 + wid * 16 + ((lane >> 4) * 4) + rg;
        if (row < n) {
#pragma unroll
            for (int nn = 0; nn < 4; ++nn) {
                int col = nn * 16 + cl;
                if (col < 40)
                    out[(size_t)row * 40 + col] = v[nn] - mx - ls;
            }
        }
    }
}

// ---------------------------------------------------------------------------
extern "C" void kernel_launch(void* const* d_in, const int* in_sizes, int n_in,
                              void* d_out, int out_size, void* d_ws, size_t ws_size,
                              hipStream_t stream)
{
    const float* x       = (const float*)d_in[0];
    const int*   ei      = (const int*)  d_in[1];
    const float* ew      = (const float*)d_in[2];
    const float* w1_rel  = (const float*)d_in[3];
    const float* b1      = (const float*)d_in[4];
    const float* w1_root = (const float*)d_in[5];
    const float* w2_rel  = (const float*)d_in[6];
    const float* b2      = (const float*)d_in[7];
    const float* w2_root = (const float*)d_in[8];
    const float* w_lin   = (const float*)d_in[9];
    const float* b_lin   = (const float*)d_in[10];
    float* out = (float*)d_out;

    const int N = in_sizes[0] / 128;   // 50000 (< 65536: u16 src pack valid)
    const int E = in_sizes[2];         // 800000

    auto align = [](char*& p, size_t bytes) {
        char* r = p;
        p += (bytes + 255) & ~(size_t)255;
        return r;
    };
    char* wp = (char*)d_ws;
    __hip_bfloat16* xb     = (__hip_bfloat16*)align(wp, (size_t)N * 128 * 2);
    __hip_bfloat16* agg1b  = (__hip_bfloat16*)align(wp, (size_t)N * 128 * 2);
    __hip_bfloat16* x1b    = (__hip_bfloat16*)align(wp, (size_t)N * 256 * 2);
    __hip_bfloat16* agg2b  = (__hip_bfloat16*)align(wp, (size_t)N * 256 * 2);
    __hip_bfloat16* x2b    = (__hip_bfloat16*)align(wp, (size_t)N * 256 * 2);
    unsigned char*  xb8    = (unsigned char*)align(wp, (size_t)N * 128);
    unsigned char*  x1b8   = (unsigned char*)align(wp, (size_t)N * 256);
    __hip_bfloat16* w1relT  = (__hip_bfloat16*)align(wp, 256 * 128 * 2);
    __hip_bfloat16* w1rootT = (__hip_bfloat16*)align(wp, 256 * 128 * 2);
    __hip_bfloat16* w2relT  = (__hip_bfloat16*)align(wp, 256 * 256 * 2);
    __hip_bfloat16* w2rootT = (__hip_bfloat16*)align(wp, 256 * 256 * 2);
    __hip_bfloat16* wlinT   = (__hip_bfloat16*)align(wp, 2 * 64 * 256 * 2);
    int*      row_ptr       = (int*)align(wp, (size_t)(N + 1) * 4);
    int*      bh_part       = (int*)align(wp, 256 * 256 * 4);
    int*      bpre          = (int*)align(wp, 256 * 4);
    int*      bend          = (int*)align(wp, 256 * 4);
    int*      bucket_cursor = (int*)align(wp, 256 * 4);
    unsigned* edges         = (unsigned*)align(wp, (size_t)E * 4);
    uint2*    part          = (uint2*)align(wp, (size_t)E * 8);

    const int nb = (N + 255) / 256;   // 196 buckets (bucket = dst >> 8)
    const int hist_blocks = (E + 256 * BH_EPB - 1) / (256 * BH_EPB);   // 196
    const int NX8 = N * 128 / 8;       // 800000

    // fused prep: partial histograms + conversions (no memset, no atomics)
    {
        long long conv = (long long)NX8 + 229376;
        int conv_blocks = (int)((conv + 255) / 256);
        prep_all<<<hist_blocks + conv_blocks, 256, 0, stream>>>(
            ei, E, hist_blocks, bh_part,
            x, xb, xb8, NX8,
            w1_rel, w1_root, w2_rel, w2_root, w_lin,
            w1relT, w1rootT, w2relT, w2rootT, wlinT);
    }
    // CSR build: reduce+scan -> partition -> per-bucket CSR
    {
        scan_bsum<<<1, 256, 0, stream>>>(bh_part, hist_blocks,
                                         bpre, bend, bucket_cursor);
        int p1_blocks = (E + 256 * P1_EPB - 1) / (256 * P1_EPB);   // 391
        part_kernel<<<p1_blocks, 256, 0, stream>>>(ei, ew, bucket_cursor, part, E);
        fill2_kernel<<<nb, 256, 0, stream>>>(part, bpre, bend, row_ptr, edges, N);
    }

    const int gather_blocks = (N * 64 + 255) / 256;
    const int gemm_grid     = ((N + 127) / 128) * 4;   // 128x64 tiles
    const int head_grid     = (N + 63) / 64;           // 64-row blocks

    // layer 1
    gather_fp8<128><<<gather_blocks, 256, 0, stream>>>(
        xb8, edges, row_ptr, agg1b, N);
    gemm_mfma<true><<<gemm_grid, 256, 0, stream>>>(
        agg1b, xb, w1relT, w1rootT, b1, x1b, x1b8, N, 128, 128);
    // layer 2
    gather_fp8<256><<<gather_blocks, 256, 0, stream>>>(
        x1b8, edges, row_ptr, agg2b, N);
    gemm_mfma<false><<<gemm_grid, 256, 0, stream>>>(
        agg2b, x1b, w2relT, w2rootT, b2, x2b, nullptr, N, 256, 256);
    // head
    head_mfma<<<head_grid, 256, 0, stream>>>(x1b, x2b, wlinT, b_lin, out, N);
}

// Round 17
// 175.136 us; speedup vs baseline: 1.0819x; 1.0819x over previous
//
#include <hip/hip_runtime.h>
#include <hip/hip_bf16.h>
#include <hip/hip_fp16.h>
#include <math.h>

// ---------------------------------------------------------------------------
// GraphConv GNN, round 16: revert GEMM/head to R14 shapes (128x128 BK=64
// dbuf; 128-row head) — R15's 128x64 retile quadrupled A re-fetch. Add
// bijective XCD-aware block swizzle (T1/m204) so the two blocks sharing an
// A-panel land on the same XCD's L2.
// ---------------------------------------------------------------------------

typedef __attribute__((ext_vector_type(8))) short short8;
typedef __attribute__((ext_vector_type(4))) float f32x4;

static __device__ __forceinline__ float bf2f(unsigned short u) {
    return __uint_as_float(((unsigned)u) << 16);
}

// ---- fp8 e4m3 helpers -----------------------------------------------------
static __device__ __forceinline__ void fp8x4_to_f32(unsigned u, float* o) {
#if __has_builtin(__builtin_amdgcn_cvt_pk_f32_fp8)
    auto lo = __builtin_amdgcn_cvt_pk_f32_fp8((int)u, false);
    auto hi = __builtin_amdgcn_cvt_pk_f32_fp8((int)u, true);
    o[0] = lo[0]; o[1] = lo[1]; o[2] = hi[0]; o[3] = hi[1];
#else
#pragma unroll
    for (int i = 0; i < 4; ++i) {
        unsigned b = (u >> (8 * i)) & 0xffu;
        unsigned short hb = (unsigned short)(((b & 0x80u) << 8) | ((b & 0x7fu) << 7));
        o[i] = __half2float(__ushort_as_half(hb)) * 256.0f;
    }
#endif
}

static __device__ __forceinline__ unsigned f32_to_fp8(float f) {
    __half h = __float2half(f * 0.00390625f);            // 2^-8
    unsigned short hb = __half_as_ushort(h);
    unsigned mag = hb & 0x7fffu;
    unsigned s = (hb >> 8) & 0x80u;
    unsigned v = (mag + 0x3fu + ((mag >> 7) & 1u)) >> 7; // RNE
    if (v > 0x7eu) v = 0x7eu;                            // clamp below NaN
    return s | v;
}

// bijective XCD-aware remap (m204): round-robin xcd -> contiguous chunks
static __device__ __forceinline__ unsigned xcd_swz(unsigned orig, unsigned nwg) {
    unsigned xcd = orig & 7u, base = orig >> 3;
    unsigned q = nwg >> 3, r = nwg & 7u;
    return (xcd < r ? xcd * (q + 1) : r * (q + 1) + (xcd - r) * q) + base;
}

#define BH_EPB 16

// ---- fused prep: bucket partial-histograms + x->bf16+fp8 + weight transposes
__global__ __launch_bounds__(256) void prep_all(
    const int* __restrict__ ei, int E, int hist_blocks,
    int* __restrict__ bh_part,
    const float* __restrict__ x, __hip_bfloat16* __restrict__ xb,
    unsigned char* __restrict__ xb8, int NX8,
    const float* __restrict__ w1_rel, const float* __restrict__ w1_root,
    const float* __restrict__ w2_rel, const float* __restrict__ w2_root,
    const float* __restrict__ w_lin,
    __hip_bfloat16* __restrict__ w1relT, __hip_bfloat16* __restrict__ w1rootT,
    __hip_bfloat16* __restrict__ w2relT, __hip_bfloat16* __restrict__ w2rootT,
    __hip_bfloat16* __restrict__ wlinT)
{
    __shared__ int lh[256];
    const int t = threadIdx.x;
    if (blockIdx.x < (unsigned)hist_blocks) {
        lh[t] = 0;
        __syncthreads();
        const int base = blockIdx.x * (256 * BH_EPB);
#pragma unroll
        for (int i = 0; i < BH_EPB; ++i) {
            int e = base + i * 256 + t;
            if (e < E) atomicAdd(&lh[ei[E + e] >> 8], 1);
        }
        __syncthreads();
        bh_part[blockIdx.x * 256 + t] = lh[t];   // coalesced row
        return;
    }
    int idx = (blockIdx.x - hist_blocks) * 256 + t;
    if (idx < NX8) {   // x -> bf16 + fp8, 8 elems/thread
        float4 a = *(const float4*)&x[(size_t)idx * 8];
        float4 b = *(const float4*)&x[(size_t)idx * 8 + 4];
        float f[8] = { a.x, a.y, a.z, a.w, b.x, b.y, b.z, b.w };
        __hip_bfloat16 o[8];
#pragma unroll
        for (int i = 0; i < 8; ++i) o[i] = __float2bfloat16(f[i]);
        *(short8*)&xb[(size_t)idx * 8] = *(short8*)o;
        unsigned p0 = 0, p1 = 0;
#pragma unroll
        for (int i = 0; i < 4; ++i) p0 |= f32_to_fp8(f[i]) << (8 * i);
#pragma unroll
        for (int i = 0; i < 4; ++i) p1 |= f32_to_fp8(f[4 + i]) << (8 * i);
        *(uint2*)&xb8[(size_t)idx * 8] = make_uint2(p0, p1);
        return;
    }
    idx -= NX8;
    if (idx < 65536) {                       // w1_rel/w1_root [128,256] -> [256,128]
        const float* src = (idx < 32768) ? w1_rel : w1_root;
        __hip_bfloat16* dst = (idx < 32768) ? w1relT : w1rootT;
        int i = idx & 32767;
        int k = i >> 8, c = i & 255;
        dst[c * 128 + k] = __float2bfloat16(src[i]);
    } else if (idx < 196608) {               // w2_rel/w2_root [256,256]^T
        int j = idx - 65536;
        const float* src = (j < 65536) ? w2_rel : w2_root;
        __hip_bfloat16* dst = (j < 65536) ? w2relT : w2rootT;
        int i = j & 65535;
        int k = i >> 8, c = i & 255;
        dst[c * 256 + k] = __float2bfloat16(src[i]);
    } else if (idx < 229376) {               // w_lin [512,40] -> [2][64][256]
        int i = idx - 196608;
        int seg = i >> 14, c = (i >> 8) & 63, k = i & 255;
        float v = (c < 40) ? w_lin[(size_t)(seg * 256 + k) * 40 + c] : 0.f;
        wlinT[i] = __float2bfloat16(v);
    }
}

// ---- reduce partial histograms (8-deep MLP) + scan ------------------------
__global__ __launch_bounds__(256) void scan_bsum(
    const int* __restrict__ bh_part, int hist_blocks,
    int* __restrict__ bpre, int* __restrict__ bend,
    int* __restrict__ bucket_cursor)
{
    __shared__ int sh[256];
    const int t = threadIdx.x;
    int a0 = 0, a1 = 0, a2 = 0, a3 = 0, a4 = 0, a5 = 0, a6 = 0, a7 = 0;
    int b = 0;
    for (; b + 8 <= hist_blocks; b += 8) {
        a0 += bh_part[(b + 0) * 256 + t];
        a1 += bh_part[(b + 1) * 256 + t];
        a2 += bh_part[(b + 2) * 256 + t];
        a3 += bh_part[(b + 3) * 256 + t];
        a4 += bh_part[(b + 4) * 256 + t];
        a5 += bh_part[(b + 5) * 256 + t];
        a6 += bh_part[(b + 6) * 256 + t];
        a7 += bh_part[(b + 7) * 256 + t];
    }
    for (; b < hist_blocks; ++b) a0 += bh_part[b * 256 + t];
    int v = ((a0 + a1) + (a2 + a3)) + ((a4 + a5) + (a6 + a7));
    sh[t] = v;
    __syncthreads();
#pragma unroll
    for (int off = 1; off < 256; off <<= 1) {
        int u = (t >= off) ? sh[t - off] : 0;
        __syncthreads();
        sh[t] += u;
        __syncthreads();
    }
    bpre[t]          = sh[t] - v;
    bend[t]          = sh[t];
    bucket_cursor[t] = sh[t] - v;
}

// ---- fill pass 1: partition edges into 256-node buckets -------------------
#define P1_EPB 8
__global__ __launch_bounds__(256) void part_kernel(
    const int* __restrict__ ei, const float* __restrict__ ew,
    int* __restrict__ bucket_cursor, uint2* __restrict__ part, int E)
{
    __shared__ int lhist[256];
    __shared__ int gbase[256];
    const int t = threadIdx.x;
    const int base = blockIdx.x * (256 * P1_EPB);
    lhist[t] = 0;
    __syncthreads();

    int pk[P1_EPB];
#pragma unroll
    for (int i = 0; i < P1_EPB; ++i) {
        int e = base + i * 256 + t;
        if (e < E) {
            int b = ei[E + e] >> 8;
            int r = atomicAdd(&lhist[b], 1);
            pk[i] = (b << 16) | r;
        } else pk[i] = -1;
    }
    __syncthreads();
    if (lhist[t] > 0) gbase[t] = atomicAdd(&bucket_cursor[t], lhist[t]);
    __syncthreads();
#pragma unroll
    for (int i = 0; i < P1_EPB; ++i) {
        if (pk[i] >= 0) {
            int e = base + i * 256 + t;
            int d = ei[E + e];
            unsigned short w16 = __half_as_ushort(__float2half(ew[e]));
            unsigned rec = ((unsigned)w16 << 16) | (unsigned)ei[e];
            int pos = gbase[pk[i] >> 16] + (pk[i] & 0xffff);
            part[pos] = make_uint2(rec, (unsigned)d);
        }
    }
}

// ---- fill pass 2: per-bucket CSR build + local scatter --------------------
__global__ __launch_bounds__(256) void fill2_kernel(
    const uint2* __restrict__ part, const int* __restrict__ bpre,
    const int* __restrict__ bend, int* __restrict__ row_ptr,
    unsigned* __restrict__ edges, int n)
{
    __shared__ int lcnt[256];
    __shared__ int excl[256];
    __shared__ int curs[256];
    const int b = blockIdx.x;
    const int t = threadIdx.x;
    const int node0 = b << 8;
    lcnt[t] = 0;
    __syncthreads();
    const int beg = bpre[b];
    const int end = bend[b];
    for (int i = beg + t; i < end; i += 256)
        atomicAdd(&lcnt[part[i].y & 255u], 1);
    __syncthreads();
    int v = lcnt[t];
    excl[t] = v;
    __syncthreads();
#pragma unroll
    for (int off = 1; off < 256; off <<= 1) {
        int u = (t >= off) ? excl[t - off] : 0;
        __syncthreads();
        excl[t] += u;
        __syncthreads();
    }
    const int base_t = beg + excl[t] - v;
    const int nd = node0 + t;
    if (nd <= n) row_ptr[nd] = base_t;
    curs[t] = base_t;
    __syncthreads();
    for (int i = beg + t; i < end; i += 256) {
        uint2 p = part[i];
        int slot = atomicAdd(&curs[p.y & 255u], 1);
        edges[slot] = p.x;
    }
}

// ---- gather (fp8 table, 4B edges): agg[v,:] = sum_e w_e * feat8[src_e,:] --
template <int C>
__global__ __launch_bounds__(256) void gather_fp8(
    const unsigned char* __restrict__ feat8,
    const unsigned* __restrict__ edges,
    const int*  __restrict__ rp,
    __hip_bfloat16* __restrict__ agg, int n)
{
    const int node = (blockIdx.x * 256 + threadIdx.x) >> 6;
    const int lane = threadIdx.x & 63;
    if (node >= n) return;
    const int beg = __builtin_amdgcn_readfirstlane(rp[node]);
    const int end = __builtin_amdgcn_readfirstlane(rp[node + 1]);

    constexpr int EPW = (C == 128) ? 8 : 4;
    constexpr int LPR = 64 / EPW;
    const int es = lane / LPR;
    const int ch = lane % LPR;
    const unsigned coff = (unsigned)ch * 16;

    float acc[16] = {};

    auto accum16 = [&](uint4 u, float w) {
        unsigned uu[4] = { u.x, u.y, u.z, u.w };
#pragma unroll
        for (int q = 0; q < 4; ++q) {
            float f[4];
            fp8x4_to_f32(uu[q], f);
#pragma unroll
            for (int i = 0; i < 4; ++i)
                acc[q * 4 + i] = fmaf(f[i], w, acc[q * 4 + i]);
        }
    };

    auto unpack_w = [](unsigned p) {
        return __half2float(__ushort_as_half((unsigned short)(p >> 16)));
    };

    for (int base = beg; base < end; base += 64) {
        const int m = min(64, end - base);
        unsigned ev = edges[base + ((lane < m) ? lane : (m - 1))];
        if (lane >= m) ev &= 0xffffu;

        int s = 0;
        for (; s + 2 * EPW <= m; s += 2 * EPW) {
            int j0 = s + es, j1 = j0 + EPW;
            unsigned p0 = (unsigned)__shfl((int)ev, j0, 64);
            unsigned p1 = (unsigned)__shfl((int)ev, j1, 64);
            uint4 u0 = *(const uint4*)(feat8 + (size_t)(p0 & 0xffffu) * C + coff);
            uint4 u1 = *(const uint4*)(feat8 + (size_t)(p1 & 0xffffu) * C + coff);
            accum16(u0, unpack_w(p0));
            accum16(u1, unpack_w(p1));
        }
        for (; s < m; s += EPW) {
            int j = min(s + es, 63);
            unsigned p = (unsigned)__shfl((int)ev, j, 64);
            uint4 u = *(const uint4*)(feat8 + (size_t)(p & 0xffffu) * C + coff);
            accum16(u, unpack_w(p));
        }
    }

#pragma unroll
    for (int k = 0; k < 16; ++k) {
        if constexpr (C == 128) {
            acc[k] += __shfl_xor(acc[k], 8, 64);
            acc[k] += __shfl_xor(acc[k], 16, 64);
            acc[k] += __shfl_xor(acc[k], 32, 64);
        } else {
            acc[k] += __shfl_xor(acc[k], 16, 64);
            acc[k] += __shfl_xor(acc[k], 32, 64);
        }
    }
    if (es == 0) {
        __hip_bfloat16 o[16];
#pragma unroll
        for (int k = 0; k < 16; ++k) o[k] = __float2bfloat16(acc[k]);
        __hip_bfloat16* op = agg + (size_t)node * C + ch * 16;
        *(short8*)op       = *(short8*)o;
        *(short8*)(op + 8) = *(short8*)(o + 8);
    }
}

// ---- MFMA GEMM: C = relu(A0@W0 + A1@W1 + bias), NC=256, bf16 in/out -------
// 128x128 tile, BK=64, double-buffered (64KB LDS), XCD-swizzled grid,
// LDS-staged coalesced epilogue.
template <bool WRITE_FP8>
__global__ __launch_bounds__(256) void gemm_mfma(
    const __hip_bfloat16* __restrict__ A0, const __hip_bfloat16* __restrict__ A1,
    const __hip_bfloat16* __restrict__ W0T, const __hip_bfloat16* __restrict__ W1T,
    const float* __restrict__ bias,
    __hip_bfloat16* __restrict__ Cmat,
    unsigned char* __restrict__ Cfp8,
    int n, int K0, int K1)
{
    __shared__ __hip_bfloat16 Asl[2][128 * 64];   // 32 KB
    __shared__ __hip_bfloat16 Bsl[2][128 * 64];   // 32 KB
    const unsigned wg = xcd_swz(blockIdx.x, gridDim.x);
    const int bm = wg >> 1;
    const int bn = wg & 1;
    const int row0 = bm * 128, col0 = bn * 128;
    const int t = threadIdx.x, lane = t & 63, wid = t >> 6;
    const int wr = wid >> 1, wc = wid & 1;

    const int S0 = K0 >> 6;
    const int S  = S0 + (K1 >> 6);

    auto stage = [&](int buf, int s) {
        const __hip_bfloat16* A;
        const __hip_bfloat16* WT;
        int K, k0;
        if (s < S0) { A = A0; WT = W0T; K = K0; k0 = s << 6; }
        else        { A = A1; WT = W1T; K = K1; k0 = (s - S0) << 6; }
#pragma unroll
        for (int i = 0; i < 4; ++i) {
            int idx = i * 256 + t;
            int r = idx >> 3, c = idx & 7;
            int gr = row0 + r; if (gr >= n) gr = n - 1;
            const __hip_bfloat16* srcA =
                A + (size_t)gr * K + k0 + ((c ^ (r & 7)) << 3);
            __builtin_amdgcn_global_load_lds(
                (const __attribute__((address_space(1))) void*)srcA,
                (__attribute__((address_space(3))) void*)&Asl[buf][idx * 8], 16, 0, 0);
            const __hip_bfloat16* srcB =
                WT + (size_t)(col0 + r) * K + k0 + ((c ^ (r & 7)) << 3);
            __builtin_amdgcn_global_load_lds(
                (const __attribute__((address_space(1))) void*)srcB,
                (__attribute__((address_space(3))) void*)&Bsl[buf][idx * 8], 16, 0, 0);
        }
    };

    f32x4 acc[4][4] = {};

    stage(0, 0);
    __syncthreads();

    for (int s = 0; s < S; ++s) {
        const int buf = s & 1;
        if (s + 1 < S) stage(buf ^ 1, s + 1);
#pragma unroll
        for (int kh = 0; kh < 2; ++kh) {
            const int cchunk = kh * 4 + (lane >> 4);
            short8 af[4], bfr[4];
#pragma unroll
            for (int m = 0; m < 4; ++m) {
                int r = wr * 64 + m * 16 + (lane & 15);
                af[m] = *(const short8*)&Asl[buf][r * 64 + ((cchunk ^ (r & 7)) << 3)];
            }
#pragma unroll
            for (int nn = 0; nn < 4; ++nn) {
                int r = wc * 64 + nn * 16 + (lane & 15);
                bfr[nn] = *(const short8*)&Bsl[buf][r * 64 + ((cchunk ^ (r & 7)) << 3)];
            }
#pragma unroll
            for (int m = 0; m < 4; ++m)
#pragma unroll
                for (int nn = 0; nn < 4; ++nn)
                    acc[m][nn] = __builtin_amdgcn_mfma_f32_16x16x32_bf16(
                        af[m], bfr[nn], acc[m][nn], 0, 0, 0);
        }
        __syncthreads();
    }

    // epilogue: bias+relu -> LDS tile -> coalesced global writes
    __hip_bfloat16* Csh = &Asl[0][0];
#pragma unroll
    for (int nn = 0; nn < 4; ++nn) {
        int lcol = wc * 64 + nn * 16 + (lane & 15);
        float b = bias[col0 + lcol];
#pragma unroll
        for (int m = 0; m < 4; ++m) {
#pragma unroll
            for (int rg = 0; rg < 4; ++rg) {
                int lrow = wr * 64 + m * 16 + ((lane >> 4) * 4) + rg;
                float v = fmaxf(acc[m][nn][rg] + b, 0.f);
                Csh[lrow * 128 + lcol] = __float2bfloat16(v);
            }
        }
    }
    __syncthreads();

#pragma unroll
    for (int it = 0; it < 8; ++it) {
        int idx = it * 256 + t;
        int r = idx >> 4, c16 = idx & 15;
        if (row0 + r < n)
            *(short8*)(Cmat + (size_t)(row0 + r) * 256 + col0 + c16 * 8) =
                *(const short8*)&Csh[r * 128 + c16 * 8];
    }
    if constexpr (WRITE_FP8) {
#pragma unroll
        for (int it = 0; it < 4; ++it) {
            int idx = it * 256 + t;
            int r = idx >> 3, c16 = idx & 7;
            if (row0 + r < n) {
                const __hip_bfloat16* src = &Csh[r * 128 + c16 * 16];
                unsigned w[4];
#pragma unroll
                for (int q = 0; q < 4; ++q) {
                    unsigned p = 0;
#pragma unroll
                    for (int i = 0; i < 4; ++i)
                        p |= f32_to_fp8(__bfloat162float(src[q * 4 + i])) << (8 * i);
                    w[q] = p;
                }
                *(uint4*)(Cfp8 + (size_t)(row0 + r) * 256 + col0 + c16 * 16) =
                    make_uint4(w[0], w[1], w[2], w[3]);
            }
        }
    }
}

// ---- head: out = log_softmax([x1|x2] @ w_lin + b_lin), MFMA fused ---------
__global__ __launch_bounds__(256) void head_mfma(
    const __hip_bfloat16* __restrict__ X1, const __hip_bfloat16* __restrict__ X2,
    const __hip_bfloat16* __restrict__ WLT,   // [2][64][256]
    const float* __restrict__ b_lin,
    float* __restrict__ out, int n)
{
    __shared__ __hip_bfloat16 Asl[128 * 64];
    __shared__ __hip_bfloat16 Bsl[64 * 64];
    const int row0 = blockIdx.x * 128;
    const int t = threadIdx.x, lane = t & 63, wid = t >> 6;

    f32x4 acc[2][4] = {};

    for (int seg = 0; seg < 2; ++seg) {
        const __hip_bfloat16* A  = seg ? X2 : X1;
        const __hip_bfloat16* WT = WLT + seg * 64 * 256;
        for (int k0 = 0; k0 < 256; k0 += 64) {
#pragma unroll
            for (int i = 0; i < 4; ++i) {
                int idx = i * 256 + t;
                int r = idx >> 3, c = idx & 7;
                int gr = row0 + r; if (gr >= n) gr = n - 1;
                const __hip_bfloat16* srcA =
                    A + (size_t)gr * 256 + k0 + ((c ^ (r & 7)) << 3);
                __builtin_amdgcn_global_load_lds(
                    (const __attribute__((address_space(1))) void*)srcA,
                    (__attribute__((address_space(3))) void*)&Asl[idx * 8], 16, 0, 0);
            }
#pragma unroll
            for (int i = 0; i < 2; ++i) {
                int idx = i * 256 + t;
                int r = idx >> 3, c = idx & 7;
                const __hip_bfloat16* srcB =
                    WT + (size_t)r * 256 + k0 + ((c ^ (r & 7)) << 3);
                __builtin_amdgcn_global_load_lds(
                    (const __attribute__((address_space(1))) void*)srcB,
                    (__attribute__((address_space(3))) void*)&Bsl[idx * 8], 16, 0, 0);
            }
            __syncthreads();
#pragma unroll
            for (int kh = 0; kh < 2; ++kh) {
                const int cchunk = kh * 4 + (lane >> 4);
                short8 af[2], bfr[4];
#pragma unroll
                for (int m = 0; m < 2; ++m) {
                    int r = wid * 32 + m * 16 + (lane & 15);
                    af[m] = *(const short8*)&Asl[r * 64 + ((cchunk ^ (r & 7)) << 3)];
                }
#pragma unroll
                for (int nn = 0; nn < 4; ++nn) {
                    int r = nn * 16 + (lane & 15);
                    bfr[nn] = *(const short8*)&Bsl[r * 64 + ((cchunk ^ (r & 7)) << 3)];
                }
#pragma unroll
                for (int m = 0; m < 2; ++m)
#pragma unroll
                    for (int nn = 0; nn < 4; ++nn)
                        acc[m][nn] = __builtin_amdgcn_mfma_f32_16x16x32_bf16(
                            af[m], bfr[nn], acc[m][nn], 0, 0, 0);
            }
            __syncthreads();
        }
    }

    const int cl = lane & 15;
    float bb[4];
#pragma unroll
    for (int nn = 0; nn < 4; ++nn) {
        int col = nn * 16 + cl;
        bb[nn] = (col < 40) ? b_lin[col] : 0.f;
    }
#pragma unroll
    for (int m = 0; m < 2; ++m) {
#pragma unroll
        for (int rg = 0; rg < 4; ++rg) {
            float v[4];
            float mx = -1e30f;
#pragma unroll
            for (int nn = 0; nn < 4; ++nn) {
                int col = nn * 16 + cl;
                v[nn] = acc[m][nn][rg] + bb[nn];
                if (col < 40) mx = fmaxf(mx, v[nn]);
            }
#pragma unroll
            for (int off = 1; off < 16; off <<= 1)
                mx = fmaxf(mx, __shfl_xor(mx, off, 64));
            float s = 0.f;
#pragma unroll
            for (int nn = 0; nn < 4; ++nn) {
                int col = nn * 16 + cl;
                if (col < 40) s += expf(v[nn] - mx);
            }
#pragma unroll
            for (int off = 1; off < 16; off <<= 1)
                s += __shfl_xor(s, off, 64);
            float ls = logf(s);
            int row = row0 + wid * 32 + m * 16 + ((lane >> 4) * 4) + rg;
            if (row < n) {
#pragma unroll
                for (int nn = 0; nn < 4; ++nn) {
                    int col = nn * 16 + cl;
                    if (col < 40)
                        out[(size_t)row * 40 + col] = v[nn] - mx - ls;
                }
            }
        }
    }
}

// ---------------------------------------------------------------------------
extern "C" void kernel_launch(void* const* d_in, const int* in_sizes, int n_in,
                              void* d_out, int out_size, void* d_ws, size_t ws_size,
                              hipStream_t stream)
{
    const float* x       = (const float*)d_in[0];
    const int*   ei      = (const int*)  d_in[1];
    const float* ew      = (const float*)d_in[2];
    const float* w1_rel  = (const float*)d_in[3];
    const float* b1      = (const float*)d_in[4];
    const float* w1_root = (const float*)d_in[5];
    const float* w2_rel  = (const float*)d_in[6];
    const float* b2      = (const float*)d_in[7];
    const float* w2_root = (const float*)d_in[8];
    const float* w_lin   = (const float*)d_in[9];
    const float* b_lin   = (const float*)d_in[10];
    float* out = (float*)d_out;

    const int N = in_sizes[0] / 128;   // 50000 (< 65536: u16 src pack valid)
    const int E = in_sizes[2];         // 800000

    auto align = [](char*& p, size_t bytes) {
        char* r = p;
        p += (bytes + 255) & ~(size_t)255;
        return r;
    };
    char* wp = (char*)d_ws;
    __hip_bfloat16* xb     = (__hip_bfloat16*)align(wp, (size_t)N * 128 * 2);
    __hip_bfloat16* agg1b  = (__hip_bfloat16*)align(wp, (size_t)N * 128 * 2);
    __hip_bfloat16* x1b    = (__hip_bfloat16*)align(wp, (size_t)N * 256 * 2);
    __hip_bfloat16* agg2b  = (__hip_bfloat16*)align(wp, (size_t)N * 256 * 2);
    __hip_bfloat16* x2b    = (__hip_bfloat16*)align(wp, (size_t)N * 256 * 2);
    unsigned char*  xb8    = (unsigned char*)align(wp, (size_t)N * 128);
    unsigned char*  x1b8   = (unsigned char*)align(wp, (size_t)N * 256);
    __hip_bfloat16* w1relT  = (__hip_bfloat16*)align(wp, 256 * 128 * 2);
    __hip_bfloat16* w1rootT = (__hip_bfloat16*)align(wp, 256 * 128 * 2);
    __hip_bfloat16* w2relT  = (__hip_bfloat16*)align(wp, 256 * 256 * 2);
    __hip_bfloat16* w2rootT = (__hip_bfloat16*)align(wp, 256 * 256 * 2);
    __hip_bfloat16* wlinT   = (__hip_bfloat16*)align(wp, 2 * 64 * 256 * 2);
    int*      row_ptr       = (int*)align(wp, (size_t)(N + 1) * 4);
    int*      bh_part       = (int*)align(wp, 256 * 256 * 4);
    int*      bpre          = (int*)align(wp, 256 * 4);
    int*      bend          = (int*)align(wp, 256 * 4);
    int*      bucket_cursor = (int*)align(wp, 256 * 4);
    unsigned* edges         = (unsigned*)align(wp, (size_t)E * 4);
    uint2*    part          = (uint2*)align(wp, (size_t)E * 8);

    const int nb = (N + 255) / 256;   // 196 buckets (bucket = dst >> 8)
    const int hist_blocks = (E + 256 * BH_EPB - 1) / (256 * BH_EPB);   // 196
    const int NX8 = N * 128 / 8;       // 800000

    // fused prep: partial histograms + conversions (no memset, no atomics)
    {
        long long conv = (long long)NX8 + 229376;
        int conv_blocks = (int)((conv + 255) / 256);
        prep_all<<<hist_blocks + conv_blocks, 256, 0, stream>>>(
            ei, E, hist_blocks, bh_part,
            x, xb, xb8, NX8,
            w1_rel, w1_root, w2_rel, w2_root, w_lin,
            w1relT, w1rootT, w2relT, w2rootT, wlinT);
    }
    // CSR build: reduce+scan -> partition -> per-bucket CSR
    {
        scan_bsum<<<1, 256, 0, stream>>>(bh_part, hist_blocks,
                                         bpre, bend, bucket_cursor);
        int p1_blocks = (E + 256 * P1_EPB - 1) / (256 * P1_EPB);   // 391
        part_kernel<<<p1_blocks, 256, 0, stream>>>(ei, ew, bucket_cursor, part, E);
        fill2_kernel<<<nb, 256, 0, stream>>>(part, bpre, bend, row_ptr, edges, N);
    }

    const int gather_blocks = (N * 64 + 255) / 256;
    const int gemm_grid     = ((N + 127) / 128) * 2;   // 128x128 tiles
    const int head_grid     = (N + 127) / 128;

    // layer 1
    gather_fp8<128><<<gather_blocks, 256, 0, stream>>>(
        xb8, edges, row_ptr, agg1b, N);
    gemm_mfma<true><<<gemm_grid, 256, 0, stream>>>(
        agg1b, xb, w1relT, w1rootT, b1, x1b, x1b8, N, 128, 128);
    // layer 2
    gather_fp8<256><<<gather_blocks, 256, 0, stream>>>(
        x1b8, edges, row_ptr, agg2b, N);
    gemm_mfma<false><<<gemm_grid, 256, 0, stream>>>(
        agg2b, x1b, w2relT, w2rootT, b2, x2b, nullptr, N, 256, 256);
    // head
    head_mfma<<<head_grid, 256, 0, stream>>>(x1b, x2b, wlinT, b_lin, out, N);
}